// Round 1
// baseline (1175.859 us; speedup 1.0000x reference)
//
#include <hip/hip_runtime.h>
#include <stdint.h>

typedef unsigned short u16;
typedef float f32x4 __attribute__((ext_vector_type(4)));
typedef short s16x8 __attribute__((ext_vector_type(8)));
typedef unsigned short u16x4 __attribute__((ext_vector_type(4)));

#define NB 16
#define NT 9
#define NN 1024
#define NDIM 768
#define NH 8
#define NHD 96
#define NM (NB*NT*NN)          // 147456 rows
#define NQK 1536               // q|k columns
#define PLANE (NN*NDIM)        // 786432 elems per (b,t) plane
#define SCALE_F 0.10206207261596575f   // 96^-0.5

typedef __attribute__((address_space(1))) const void gvoid_t;
typedef __attribute__((address_space(3))) void lvoid_t;
#define GLOAD_LDS16(gp, lp) __builtin_amdgcn_global_load_lds((gvoid_t*)(gp), (lvoid_t*)(lp), 16, 0, 0)

__device__ __forceinline__ unsigned f2bf_u(float x) {
    unsigned u = __builtin_bit_cast(unsigned, x);
    return (u + 0x7FFFu + ((u >> 16) & 1u)) >> 16;   // RNE
}
__device__ __forceinline__ void cvt8(uint4 v, float* f) {
    f[0] = __builtin_bit_cast(float, v.x << 16);
    f[1] = __builtin_bit_cast(float, v.x & 0xFFFF0000u);
    f[2] = __builtin_bit_cast(float, v.y << 16);
    f[3] = __builtin_bit_cast(float, v.y & 0xFFFF0000u);
    f[4] = __builtin_bit_cast(float, v.z << 16);
    f[5] = __builtin_bit_cast(float, v.z & 0xFFFF0000u);
    f[6] = __builtin_bit_cast(float, v.w << 16);
    f[7] = __builtin_bit_cast(float, v.w & 0xFFFF0000u);
}
__device__ __forceinline__ uint4 pack8(const float* f) {
    uint4 o;
    o.x = f2bf_u(f[0]) | (f2bf_u(f[1]) << 16);
    o.y = f2bf_u(f[2]) | (f2bf_u(f[3]) << 16);
    o.z = f2bf_u(f[4]) | (f2bf_u(f[5]) << 16);
    o.w = f2bf_u(f[6]) | (f2bf_u(f[7]) << 16);
    return o;
}

// ---- K0a: W_qkv[:, 0:1536] -> Wqkt[j][c] bf16 (B^T layout for the QK GEMM)
__global__ void transpose_w(const float* __restrict__ Wqkv, u16* __restrict__ Wqkt) {
    __shared__ u16 t[32][33];
    int j0 = blockIdx.x * 32, c0 = blockIdx.y * 32;
    int tx = threadIdx.x, ty = threadIdx.y;
    t[ty][tx] = (u16)f2bf_u(Wqkv[(size_t)(c0 + ty) * 2304 + j0 + tx]);
    __syncthreads();
    Wqkt[(size_t)(j0 + ty) * 768 + c0 + tx] = t[tx][ty];
}

// ---- K0b: Wvot[c2][c] = sum_e Wout[e][c2] * Wv[c][e]  (== (W_v@W_out)^T, bf16)
__global__ void wvo_gemm(const float* __restrict__ Wqkv, const float* __restrict__ Wout,
                         u16* __restrict__ Wvot) {
    __shared__ float la[32][33];  // la[e][c2]
    __shared__ float lb[32][33];  // lb[c][e]
    int c0 = blockIdx.x * 32, c20 = blockIdx.y * 32;
    int tx = threadIdx.x, ty = threadIdx.y;
    float acc = 0.f;
    for (int e0 = 0; e0 < 768; e0 += 32) {
        la[ty][tx] = Wout[(size_t)(e0 + ty) * 768 + c20 + tx];
        lb[ty][tx] = Wqkv[(size_t)(c0 + ty) * 2304 + 1536 + e0 + tx];
        __syncthreads();
        #pragma unroll
        for (int e = 0; e < 32; ++e)
            acc = fmaf(la[e][ty], lb[tx][e], acc);
        __syncthreads();
    }
    Wvot[(size_t)(c20 + ty) * 768 + c0 + tx] = (u16)f2bf_u(acc);
}

// ---- K0c: x fp32 -> xb bf16
__global__ __launch_bounds__(256) void cvt_x(const float* __restrict__ x, u16* __restrict__ xb) {
    size_t i = (size_t)blockIdx.x * 256 + threadIdx.x;
    f32x4 v = ((const f32x4*)x)[i];
    u16x4 o;
    o.x = (u16)f2bf_u(v.x); o.y = (u16)f2bf_u(v.y);
    o.z = (u16)f2bf_u(v.z); o.w = (u16)f2bf_u(v.w);
    ((u16x4*)xb)[i] = o;
}

// ---- GEMM: C[M][N] = A[M][K] * Bt[N][K]^T ; WM==0: bf16 C ; WM==1: f32 C + bias
template<int WM>
__global__ __launch_bounds__(256, 2)
void gemm_bt(const u16* __restrict__ A, const u16* __restrict__ Bt,
             void* __restrict__ Cv, const float* __restrict__ bias,
             int M, int N, int K) {
    __shared__ __align__(16) u16 lA[128 * 64];
    __shared__ __align__(16) u16 lB[128 * 64];
    const int tid  = threadIdx.x;
    const int lane = tid & 63;
    const int nbx  = N >> 7;
    const int nb   = gridDim.x;
    const int cpx  = nb >> 3;                       // grid % 8 == 0 guaranteed
    const int bid  = blockIdx.x;
    const int swz  = (bid & 7) * cpx + (bid >> 3);  // XCD-aware swizzle (bijective)
    const int bx   = swz % nbx, by = swz / nbx;
    const long m0  = (long)by << 7;
    const int n0   = bx << 7;
    const int wm   = ((tid >> 7) & 1) << 6;
    const int wn   = ((tid >> 6) & 1) << 6;

    f32x4 acc[4][4] = {};

    const int rA  = tid >> 3;     // staging row within 32-row group
    const int seg = tid & 7;      // 16B segment within 128B row
    const u16* Ab = A + m0 * K + seg * 8;
    const u16* Bb = Bt + (long)n0 * K + seg * 8;
    u16* lAb = lA + (size_t)(tid & 192) * 8;  // wave-uniform LDS base
    u16* lBb = lB + (size_t)(tid & 192) * 8;

    const int ar = (wm + (lane & 15)) * 64 + (lane >> 4) * 8;
    const int br = (wn + (lane & 15)) * 64 + (lane >> 4) * 8;

    for (int k0 = 0; k0 < K; k0 += 64) {
        #pragma unroll
        for (int i = 0; i < 4; ++i) {
            GLOAD_LDS16(Ab + (size_t)(i * 32 + rA) * K + k0, lAb + i * 2048);
            GLOAD_LDS16(Bb + (size_t)(i * 32 + rA) * K + k0, lBb + i * 2048);
        }
        __syncthreads();
        #pragma unroll
        for (int kk = 0; kk < 64; kk += 32) {
            s16x8 af[4], bfr[4];
            #pragma unroll
            for (int mi = 0; mi < 4; ++mi)
                af[mi] = *(const s16x8*)&lA[ar + mi * 1024 + kk];
            #pragma unroll
            for (int ni = 0; ni < 4; ++ni)
                bfr[ni] = *(const s16x8*)&lB[br + ni * 1024 + kk];
            #pragma unroll
            for (int mi = 0; mi < 4; ++mi)
                #pragma unroll
                for (int ni = 0; ni < 4; ++ni)
                    acc[mi][ni] = __builtin_amdgcn_mfma_f32_16x16x32_bf16(
                        af[mi], bfr[ni], acc[mi][ni], 0, 0, 0);
        }
        __syncthreads();
    }

    const int crow = wm + ((lane >> 4) << 2);
    const int ccol = n0 + wn + (lane & 15);
    if constexpr (WM == 0) {
        u16* C = (u16*)Cv;
        #pragma unroll
        for (int mi = 0; mi < 4; ++mi)
            #pragma unroll
            for (int ni = 0; ni < 4; ++ni) {
                long r = m0 + crow + mi * 16;
                int  c = ccol + ni * 16;
                #pragma unroll
                for (int i = 0; i < 4; ++i)
                    C[(r + i) * (long)N + c] = (u16)f2bf_u(acc[mi][ni][i]);
            }
    } else {
        float* C = (float*)Cv;
        #pragma unroll
        for (int mi = 0; mi < 4; ++mi)
            #pragma unroll
            for (int ni = 0; ni < 4; ++ni) {
                long r = m0 + crow + mi * 16;
                int  c = ccol + ni * 16;
                float bv = bias[c];
                #pragma unroll
                for (int i = 0; i < 4; ++i)
                    C[(r + i) * (long)N + c] = acc[mi][ni][i] + bv;
            }
    }
}

// ---- K2: partial dots[b,h,t,s] = sum_{n,d} q*k over this block's (n,d)-chunk
__global__ __launch_bounds__(256)
void dots_partial(const u16* __restrict__ QK, float* __restrict__ part) {
    const int tid = threadIdx.x;
    const int ch  = blockIdx.x;   // 16 chunks
    const int h   = blockIdx.y;   // 8
    const int b   = blockIdx.z;   // 16
    const size_t tstride = (size_t)NN * NQK;
    const u16* base = QK + (size_t)b * 9 * tstride + h * NHD;

    float acc[9][9] = {};
    #pragma unroll 1
    for (int j = 0; j < 3; ++j) {
        int p  = ch * 768 + j * 256 + tid;   // 16B piece index, < 12288
        int n  = p / 12, dc = p % 12;
        const u16* qp = base + (size_t)n * NQK + dc * 8;
        float qf[9][8];
        #pragma unroll
        for (int t = 0; t < 9; ++t) {
            uint4 qv = *(const uint4*)(qp + (size_t)t * tstride);
            cvt8(qv, qf[t]);
        }
        #pragma unroll
        for (int s = 0; s < 9; ++s) {
            uint4 kv = *(const uint4*)(qp + (size_t)s * tstride + 768);
            float kf[8]; cvt8(kv, kf);
            #pragma unroll
            for (int t = 0; t < 9; ++t)
                #pragma unroll
                for (int e = 0; e < 8; ++e)
                    acc[t][s] = fmaf(qf[t][e], kf[e], acc[t][s]);
        }
    }
    // wave butterfly reduce, then cross-wave via LDS
    #pragma unroll
    for (int t = 0; t < 9; ++t)
        #pragma unroll
        for (int s = 0; s < 9; ++s) {
            float v = acc[t][s];
            #pragma unroll
            for (int m = 1; m < 64; m <<= 1) v += __shfl_xor(v, m, 64);
            acc[t][s] = v;
        }
    __shared__ float red[4][81];
    if ((tid & 63) == 0) {
        #pragma unroll
        for (int t = 0; t < 9; ++t)
            #pragma unroll
            for (int s = 0; s < 9; ++s) red[tid >> 6][t * 9 + s] = acc[t][s];
    }
    __syncthreads();
    if (tid < 81) {
        float v = red[0][tid] + red[1][tid] + red[2][tid] + red[3][tid];
        part[((size_t)ch * 128 + b * 8 + h) * 81 + tid] = v;
    }
}

// ---- K3: sum partials -> scale -> softmax(s) -> mean(h) -> @W_temp + b_temp -> ta[b][t][s]
__global__ void finalize_ta(const float* __restrict__ part, const float* __restrict__ Wtmp,
                            const float* __restrict__ btmp, float* __restrict__ ta) {
    const int b = blockIdx.x;
    const int tid = threadIdx.x;
    __shared__ float attn_l[8][9][9];
    if (tid < 72) {
        int h = tid / 9, t = tid % 9;
        float v[9];
        #pragma unroll
        for (int s = 0; s < 9; ++s) {
            float a = 0.f;
            for (int ch = 0; ch < 16; ++ch)
                a += part[((size_t)ch * 128 + b * 8 + h) * 81 + t * 9 + s];
            v[s] = a * (SCALE_F / 1024.0f);
        }
        float mx = v[0];
        #pragma unroll
        for (int s = 1; s < 9; ++s) mx = fmaxf(mx, v[s]);
        float den = 0.f;
        #pragma unroll
        for (int s = 0; s < 9; ++s) { v[s] = __expf(v[s] - mx); den += v[s]; }
        float inv = 1.0f / den;
        #pragma unroll
        for (int s = 0; s < 9; ++s) attn_l[h][t][s] = v[s] * inv;
    }
    __syncthreads();
    if (tid < 81) {
        int t = tid / 9, j = tid % 9;
        float o = btmp[j];
        #pragma unroll
        for (int s = 0; s < 9; ++s) {
            float am = 0.f;
            #pragma unroll
            for (int hh = 0; hh < 8; ++hh) am += attn_l[hh][t][s];
            o = fmaf(am * 0.125f, Wtmp[s * 9 + j], o);
        }
        ta[(size_t)b * 81 + t * 9 + j] = o;
    }
}

// ---- K4: in-place temporal mix: xb[b,t,:] = sum_s ta[b,t,s] * xb[b,s,:]
__global__ __launch_bounds__(256)
void tmix(u16* __restrict__ xb, const float* __restrict__ ta) {
    const int b = blockIdx.y;
    const int tid = threadIdx.x;
    __shared__ float tl[81];
    if (tid < 81) tl[tid] = ta[(size_t)b * 81 + tid];
    __syncthreads();
    size_t off = ((size_t)blockIdx.x * 256 + tid) * 8;
    u16* pb = xb + (size_t)b * 9 * PLANE + off;
    float acc[9][8] = {};
    #pragma unroll
    for (int s = 0; s < 9; ++s) {
        uint4 xv = *(const uint4*)(pb + (size_t)s * PLANE);
        float xf[8]; cvt8(xv, xf);
        #pragma unroll
        for (int t = 0; t < 9; ++t) {
            float w = tl[t * 9 + s];
            #pragma unroll
            for (int e = 0; e < 8; ++e) acc[t][e] = fmaf(w, xf[e], acc[t][e]);
        }
    }
    #pragma unroll
    for (int t = 0; t < 9; ++t)
        *(uint4*)(pb + (size_t)t * PLANE) = pack8(acc[t]);
}

extern "C" void kernel_launch(void* const* d_in, const int* in_sizes, int n_in,
                              void* d_out, int out_size, void* d_ws, size_t ws_size,
                              hipStream_t stream) {
    (void)in_sizes; (void)n_in; (void)out_size; (void)ws_size;
    const float* x    = (const float*)d_in[0];
    const float* Wqkv = (const float*)d_in[1];
    const float* Wtmp = (const float*)d_in[2];
    const float* btmp = (const float*)d_in[3];
    const float* Wout = (const float*)d_in[4];
    const float* bout = (const float*)d_in[5];

    char* ws = (char*)d_ws;
    u16*   xb   = (u16*)ws;                       // 226,492,416 B
    u16*   Wqkt = (u16*)(ws + 226492416ull);      //   2,359,296 B
    u16*   Wvot = (u16*)(ws + 228851712ull);      //   1,179,648 B
    float* part = (float*)(ws + 230031360ull);    //     663,552 B
    float* ta   = (float*)(ws + 230694912ull);    //       5,184 B
    u16*   QK   = (u16*)d_out;                    // reuse d_out (exactly 452,984,832 B) as bf16 QK scratch

    transpose_w<<<dim3(48, 24), dim3(32, 32), 0, stream>>>(Wqkv, Wqkt);
    wvo_gemm<<<dim3(24, 24), dim3(32, 32), 0, stream>>>(Wqkv, Wout, Wvot);
    cvt_x<<<110592, 256, 0, stream>>>(x, xb);
    gemm_bt<0><<<13824, 256, 0, stream>>>(xb, Wqkt, (void*)QK, nullptr, NM, NQK, NDIM);
    dots_partial<<<dim3(16, 8, 16), 256, 0, stream>>>(QK, part);
    finalize_ta<<<16, 128, 0, stream>>>(part, Wtmp, btmp, ta);
    tmix<<<dim3(384, 16), 256, 0, stream>>>(xb, ta);
    gemm_bt<1><<<6912, 256, 0, stream>>>(xb, Wvot, d_out, bout, NM, NDIM, NDIM);
}

// Round 2
// 1022.510 us; speedup vs baseline: 1.1500x; 1.1500x over previous
//
#include <hip/hip_runtime.h>
#include <stdint.h>

typedef unsigned short u16;
typedef float f32x4 __attribute__((ext_vector_type(4)));
typedef short s16x8 __attribute__((ext_vector_type(8)));
typedef unsigned short u16x4 __attribute__((ext_vector_type(4)));

#define NB 16
#define NT 9
#define NN 1024
#define NDIM 768
#define NH 8
#define NHD 96
#define NM (NB*NT*NN)          // 147456 rows
#define NQK 1536               // q|k columns
#define PLANE (NN*NDIM)        // 786432 elems per (b,t) plane
#define SCALE_F 0.10206207261596575f   // 96^-0.5

typedef __attribute__((address_space(1))) const void gvoid_t;
typedef __attribute__((address_space(3))) void lvoid_t;
#define GLOAD_LDS16(gp, lp) __builtin_amdgcn_global_load_lds((gvoid_t*)(gp), (lvoid_t*)(lp), 16, 0, 0)

__device__ __forceinline__ unsigned f2bf_u(float x) {
    unsigned u = __builtin_bit_cast(unsigned, x);
    return (u + 0x7FFFu + ((u >> 16) & 1u)) >> 16;   // RNE
}
__device__ __forceinline__ void cvt8(uint4 v, float* f) {
    f[0] = __builtin_bit_cast(float, v.x << 16);
    f[1] = __builtin_bit_cast(float, v.x & 0xFFFF0000u);
    f[2] = __builtin_bit_cast(float, v.y << 16);
    f[3] = __builtin_bit_cast(float, v.y & 0xFFFF0000u);
    f[4] = __builtin_bit_cast(float, v.z << 16);
    f[5] = __builtin_bit_cast(float, v.z & 0xFFFF0000u);
    f[6] = __builtin_bit_cast(float, v.w << 16);
    f[7] = __builtin_bit_cast(float, v.w & 0xFFFF0000u);
}
__device__ __forceinline__ uint4 pack8(const float* f) {
    uint4 o;
    o.x = f2bf_u(f[0]) | (f2bf_u(f[1]) << 16);
    o.y = f2bf_u(f[2]) | (f2bf_u(f[3]) << 16);
    o.z = f2bf_u(f[4]) | (f2bf_u(f[5]) << 16);
    o.w = f2bf_u(f[6]) | (f2bf_u(f[7]) << 16);
    return o;
}

// ---- K0a: W_qkv[:, 0:1536] -> Wqkt[j][c] bf16 (B^T layout for the QK GEMM)
__global__ void transpose_w(const float* __restrict__ Wqkv, u16* __restrict__ Wqkt) {
    __shared__ u16 t[32][33];
    int j0 = blockIdx.x * 32, c0 = blockIdx.y * 32;
    int tx = threadIdx.x, ty = threadIdx.y;
    t[ty][tx] = (u16)f2bf_u(Wqkv[(size_t)(c0 + ty) * 2304 + j0 + tx]);
    __syncthreads();
    Wqkt[(size_t)(j0 + ty) * 768 + c0 + tx] = t[tx][ty];
}

// ---- K0b: Wvot[c2][c] = sum_e Wout[e][c2] * Wv[c][e]  (== (W_v@W_out)^T, bf16)
__global__ void wvo_gemm(const float* __restrict__ Wqkv, const float* __restrict__ Wout,
                         u16* __restrict__ Wvot) {
    __shared__ float la[32][33];  // la[e][c2]
    __shared__ float lb[32][33];  // lb[c][e]
    int c0 = blockIdx.x * 32, c20 = blockIdx.y * 32;
    int tx = threadIdx.x, ty = threadIdx.y;
    float acc = 0.f;
    for (int e0 = 0; e0 < 768; e0 += 32) {
        la[ty][tx] = Wout[(size_t)(e0 + ty) * 768 + c20 + tx];
        lb[ty][tx] = Wqkv[(size_t)(c0 + ty) * 2304 + 1536 + e0 + tx];
        __syncthreads();
        #pragma unroll
        for (int e = 0; e < 32; ++e)
            acc = fmaf(la[e][ty], lb[tx][e], acc);
        __syncthreads();
    }
    Wvot[(size_t)(c20 + ty) * 768 + c0 + tx] = (u16)f2bf_u(acc);
}

// ---- K0c: x fp32 -> xb bf16
__global__ __launch_bounds__(256) void cvt_x(const float* __restrict__ x, u16* __restrict__ xb) {
    size_t i = (size_t)blockIdx.x * 256 + threadIdx.x;
    f32x4 v = ((const f32x4*)x)[i];
    u16x4 o;
    o.x = (u16)f2bf_u(v.x); o.y = (u16)f2bf_u(v.y);
    o.z = (u16)f2bf_u(v.z); o.w = (u16)f2bf_u(v.w);
    ((u16x4*)xb)[i] = o;
}

// ---- 256x256-tile deep-pipelined GEMM: C[M][N] = A[M][768] * Bt[N][768]^T
// 512 thr (8 waves 2Mx4N), BK=32, 4 LDS buffers (128KB), T2 swizzle,
// counted vmcnt (never 0 mid-loop), raw s_barrier, setprio around MFMA.
// WM==0: bf16 C ; WM==1: f32 C + bias
#define SWZ(a) ((a) ^ ((((a) >> 7) & 3) << 4))
template<int WM>
__global__ __launch_bounds__(512, 2)
void gemm256(const u16* __restrict__ A, const u16* __restrict__ Bt,
             void* __restrict__ Cv, const float* __restrict__ bias, int N) {
    constexpr int K = 768;
    constexpr int KT = 24;                 // K-tiles of 32
    __shared__ __align__(16) u16 lds[65536];   // 4 bufs x (A 16KB + B 16KB)
    const int tid  = threadIdx.x;
    const int lane = tid & 63;
    const int wid  = tid >> 6;
    const int wr   = wid >> 2;             // 0..1  (m-half, 128 rows)
    const int wc   = wid & 3;              // 0..3  (n-quarter, 64 cols)
    const int nbx  = N >> 8;
    const int cpx  = (int)gridDim.x >> 3;
    const int bid  = (int)blockIdx.x;
    const int swzb = (bid & 7) * cpx + (bid >> 3);   // bijective XCD swizzle
    const int bx   = swzb % nbx, by = swzb / nbx;
    const long m0  = (long)by << 8;
    const long n0  = (long)bx << 8;

    // --- staging precompute: thread's 2 dest-chunks per operand, pre-swizzled source
    const u16 *ag0, *ag1, *bg0, *bg1;
    u16 *ad0, *ad1, *bd0, *bd1;
    {
        int a0 = tid * 16, a1 = 8192 + tid * 16;
        int p0 = SWZ(a0), p1 = SWZ(a1);
        ag0 = A  + (m0 + (p0 >> 6)) * K + ((p0 & 63) >> 1);
        ag1 = A  + (m0 + (p1 >> 6)) * K + ((p1 & 63) >> 1);
        bg0 = Bt + (n0 + (p0 >> 6)) * K + ((p0 & 63) >> 1);
        bg1 = Bt + (n0 + (p1 >> 6)) * K + ((p1 & 63) >> 1);
        u16* wbase = (u16*)lds + (size_t)(tid & ~63) * 8;   // lane*16B implicit
        ad0 = wbase;          ad1 = wbase + 4096;
        bd0 = wbase + 8192;   bd1 = wbase + 12288;
    }

    // --- fragment LDS byte offsets (loop-invariant, swizzled)
    int aoff[8], boff[4];
    #pragma unroll
    for (int mi = 0; mi < 8; ++mi) {
        int row = wr * 128 + mi * 16 + (lane & 15);
        int byt = row * 64 + ((lane >> 4) << 4);
        aoff[mi] = SWZ(byt);
    }
    #pragma unroll
    for (int ni = 0; ni < 4; ++ni) {
        int row = wc * 64 + ni * 16 + (lane & 15);
        int byt = row * 64 + ((lane >> 4) << 4);
        boff[ni] = 16384 + SWZ(byt);
    }

    f32x4 acc[8][4] = {};

    #define STAGE_A(tt) { const int b_ = ((tt) & 3) * 16384; const int k_ = (tt) * 32; \
        GLOAD_LDS16(ag0 + k_, ad0 + b_); GLOAD_LDS16(ag1 + k_, ad1 + b_); }
    #define STAGE_B(tt) { const int b_ = ((tt) & 3) * 16384; const int k_ = (tt) * 32; \
        GLOAD_LDS16(bg0 + k_, bd0 + b_); GLOAD_LDS16(bg1 + k_, bd1 + b_); }

    // prologue: tiles 0,1,2 in flight (12 loads/thread); wait tile0 (keep 8 newest outstanding)
    STAGE_A(0); STAGE_B(0);
    STAGE_A(1); STAGE_B(1);
    STAGE_A(2); STAGE_B(2);
    asm volatile("s_waitcnt vmcnt(8)" ::: "memory");
    __builtin_amdgcn_s_barrier();

    for (int t = 0; t < KT; ++t) {
        const char* lp = (const char*)lds + ((t & 3) << 15);
        s16x8 bf[4];
        {   // ---- phase A: frags m0-3 x n0-3, stage next A
            s16x8 af[4];
            #pragma unroll
            for (int mi = 0; mi < 4; ++mi) af[mi] = *(const s16x8*)(lp + aoff[mi]);
            #pragma unroll
            for (int ni = 0; ni < 4; ++ni) bf[ni] = *(const s16x8*)(lp + boff[ni]);
            if (t + 3 < KT) STAGE_A(t + 3);
            __builtin_amdgcn_s_setprio(1);
            #pragma unroll
            for (int mi = 0; mi < 4; ++mi)
                #pragma unroll
                for (int ni = 0; ni < 4; ++ni)
                    acc[mi][ni] = __builtin_amdgcn_mfma_f32_16x16x32_bf16(
                        af[mi], bf[ni], acc[mi][ni], 0, 0, 0);
            __builtin_amdgcn_s_setprio(0);
        }
        __builtin_amdgcn_s_barrier();
        {   // ---- phase B: frags m4-7 x n0-3 (bf reused), stage next B
            s16x8 af[4];
            #pragma unroll
            for (int mi = 0; mi < 4; ++mi) af[mi] = *(const s16x8*)(lp + aoff[4 + mi]);
            if (t + 3 < KT) STAGE_B(t + 3);
            __builtin_amdgcn_s_setprio(1);
            #pragma unroll
            for (int mi = 0; mi < 4; ++mi)
                #pragma unroll
                for (int ni = 0; ni < 4; ++ni)
                    acc[4 + mi][ni] = __builtin_amdgcn_mfma_f32_16x16x32_bf16(
                        af[mi], bf[ni], acc[4 + mi][ni], 0, 0, 0);
            __builtin_amdgcn_s_setprio(0);
        }
        // counted wait: guarantee tile t+1 resident before next iter reads it
        if (t < KT - 3)       { asm volatile("s_waitcnt vmcnt(8)" ::: "memory"); }
        else if (t == KT - 3) { asm volatile("s_waitcnt vmcnt(4)" ::: "memory"); }
        else if (t == KT - 2) { asm volatile("s_waitcnt vmcnt(0)" ::: "memory"); }
        __builtin_amdgcn_s_barrier();
    }
    #undef STAGE_A
    #undef STAGE_B

    // ---- epilogue
    const int crow = (lane >> 4) << 2;
    const int ccol = lane & 15;
    if constexpr (WM == 0) {
        u16* C = (u16*)Cv;
        #pragma unroll
        for (int mi = 0; mi < 8; ++mi)
            #pragma unroll
            for (int ni = 0; ni < 4; ++ni) {
                long r = m0 + wr * 128 + mi * 16 + crow;
                long c = n0 + wc * 64 + ni * 16 + ccol;
                #pragma unroll
                for (int i = 0; i < 4; ++i)
                    C[(r + i) * (long)N + c] = (u16)f2bf_u(acc[mi][ni][i]);
            }
    } else {
        float* C = (float*)Cv;
        #pragma unroll
        for (int mi = 0; mi < 8; ++mi)
            #pragma unroll
            for (int ni = 0; ni < 4; ++ni) {
                long r = m0 + wr * 128 + mi * 16 + crow;
                long c = n0 + wc * 64 + ni * 16 + ccol;
                float bv = bias[c];
                #pragma unroll
                for (int i = 0; i < 4; ++i)
                    C[(r + i) * (long)N + c] = acc[mi][ni][i] + bv;
            }
    }
}

// ---- K2: partial dots[b,h,t,s] = sum_{n,d} q*k over this block's (n,d)-chunk
__global__ __launch_bounds__(256)
void dots_partial(const u16* __restrict__ QK, float* __restrict__ part) {
    const int tid = threadIdx.x;
    const int ch  = blockIdx.x;   // 16 chunks
    const int h   = blockIdx.y;   // 8
    const int b   = blockIdx.z;   // 16
    const size_t tstride = (size_t)NN * NQK;
    const u16* base = QK + (size_t)b * 9 * tstride + h * NHD;

    float acc[9][9] = {};
    #pragma unroll 1
    for (int j = 0; j < 3; ++j) {
        int p  = ch * 768 + j * 256 + tid;   // 16B piece index, < 12288
        int n  = p / 12, dc = p % 12;
        const u16* qp = base + (size_t)n * NQK + dc * 8;
        float qf[9][8];
        #pragma unroll
        for (int t = 0; t < 9; ++t) {
            uint4 qv = *(const uint4*)(qp + (size_t)t * tstride);
            cvt8(qv, qf[t]);
        }
        #pragma unroll
        for (int s = 0; s < 9; ++s) {
            uint4 kv = *(const uint4*)(qp + (size_t)s * tstride + 768);
            float kf[8]; cvt8(kv, kf);
            #pragma unroll
            for (int t = 0; t < 9; ++t)
                #pragma unroll
                for (int e = 0; e < 8; ++e)
                    acc[t][s] = fmaf(qf[t][e], kf[e], acc[t][s]);
        }
    }
    // wave butterfly reduce, then cross-wave via LDS
    #pragma unroll
    for (int t = 0; t < 9; ++t)
        #pragma unroll
        for (int s = 0; s < 9; ++s) {
            float v = acc[t][s];
            #pragma unroll
            for (int m = 1; m < 64; m <<= 1) v += __shfl_xor(v, m, 64);
            acc[t][s] = v;
        }
    __shared__ float red[4][81];
    if ((tid & 63) == 0) {
        #pragma unroll
        for (int t = 0; t < 9; ++t)
            #pragma unroll
            for (int s = 0; s < 9; ++s) red[tid >> 6][t * 9 + s] = acc[t][s];
    }
    __syncthreads();
    if (tid < 81) {
        float v = red[0][tid] + red[1][tid] + red[2][tid] + red[3][tid];
        part[((size_t)ch * 128 + b * 8 + h) * 81 + tid] = v;
    }
}

// ---- K3: sum partials -> scale -> softmax(s) -> mean(h) -> @W_temp + b_temp -> ta[b][t][s]
__global__ void finalize_ta(const float* __restrict__ part, const float* __restrict__ Wtmp,
                            const float* __restrict__ btmp, float* __restrict__ ta) {
    const int b = blockIdx.x;
    const int tid = threadIdx.x;
    __shared__ float attn_l[8][9][9];
    if (tid < 72) {
        int h = tid / 9, t = tid % 9;
        float v[9];
        #pragma unroll
        for (int s = 0; s < 9; ++s) {
            float a = 0.f;
            for (int ch = 0; ch < 16; ++ch)
                a += part[((size_t)ch * 128 + b * 8 + h) * 81 + t * 9 + s];
            v[s] = a * (SCALE_F / 1024.0f);
        }
        float mx = v[0];
        #pragma unroll
        for (int s = 1; s < 9; ++s) mx = fmaxf(mx, v[s]);
        float den = 0.f;
        #pragma unroll
        for (int s = 0; s < 9; ++s) { v[s] = __expf(v[s] - mx); den += v[s]; }
        float inv = 1.0f / den;
        #pragma unroll
        for (int s = 0; s < 9; ++s) attn_l[h][t][s] = v[s] * inv;
    }
    __syncthreads();
    if (tid < 81) {
        int t = tid / 9, j = tid % 9;
        float o = btmp[j];
        #pragma unroll
        for (int s = 0; s < 9; ++s) {
            float am = 0.f;
            #pragma unroll
            for (int hh = 0; hh < 8; ++hh) am += attn_l[hh][t][s];
            o = fmaf(am * 0.125f, Wtmp[s * 9 + j], o);
        }
        ta[(size_t)b * 81 + t * 9 + j] = o;
    }
}

// ---- K4: in-place temporal mix: xb[b,t,:] = sum_s ta[b,t,s] * xb[b,s,:]
__global__ __launch_bounds__(256)
void tmix(u16* __restrict__ xb, const float* __restrict__ ta) {
    const int b = blockIdx.y;
    const int tid = threadIdx.x;
    __shared__ float tl[81];
    if (tid < 81) tl[tid] = ta[(size_t)b * 81 + tid];
    __syncthreads();
    size_t off = ((size_t)blockIdx.x * 256 + tid) * 8;
    u16* pb = xb + (size_t)b * 9 * PLANE + off;
    float acc[9][8] = {};
    #pragma unroll
    for (int s = 0; s < 9; ++s) {
        uint4 xv = *(const uint4*)(pb + (size_t)s * PLANE);
        float xf[8]; cvt8(xv, xf);
        #pragma unroll
        for (int t = 0; t < 9; ++t) {
            float w = tl[t * 9 + s];
            #pragma unroll
            for (int e = 0; e < 8; ++e) acc[t][e] = fmaf(w, xf[e], acc[t][e]);
        }
    }
    #pragma unroll
    for (int t = 0; t < 9; ++t)
        *(uint4*)(pb + (size_t)t * PLANE) = pack8(acc[t]);
}

extern "C" void kernel_launch(void* const* d_in, const int* in_sizes, int n_in,
                              void* d_out, int out_size, void* d_ws, size_t ws_size,
                              hipStream_t stream) {
    (void)in_sizes; (void)n_in; (void)out_size; (void)ws_size;
    const float* x    = (const float*)d_in[0];
    const float* Wqkv = (const float*)d_in[1];
    const float* Wtmp = (const float*)d_in[2];
    const float* btmp = (const float*)d_in[3];
    const float* Wout = (const float*)d_in[4];
    const float* bout = (const float*)d_in[5];

    char* ws = (char*)d_ws;
    u16*   xb   = (u16*)ws;                       // 226,492,416 B
    u16*   Wqkt = (u16*)(ws + 226492416ull);      //   2,359,296 B
    u16*   Wvot = (u16*)(ws + 228851712ull);      //   1,179,648 B
    float* part = (float*)(ws + 230031360ull);    //     663,552 B
    float* ta   = (float*)(ws + 230694912ull);    //       5,184 B
    u16*   QK   = (u16*)d_out;                    // reuse d_out (452,984,832 B) as bf16 QK scratch

    transpose_w<<<dim3(48, 24), dim3(32, 32), 0, stream>>>(Wqkv, Wqkt);
    wvo_gemm<<<dim3(24, 24), dim3(32, 32), 0, stream>>>(Wqkv, Wout, Wvot);
    cvt_x<<<110592, 256, 0, stream>>>(x, xb);
    gemm256<0><<<3456, 512, 0, stream>>>(xb, Wqkt, (void*)QK, nullptr, NQK);
    dots_partial<<<dim3(16, 8, 16), 256, 0, stream>>>(QK, part);
    finalize_ta<<<16, 128, 0, stream>>>(part, Wtmp, btmp, ta);
    tmix<<<dim3(384, 16), 256, 0, stream>>>(xb, ta);
    gemm256<1><<<1728, 512, 0, stream>>>(xb, Wvot, d_out, bout, NDIM);
}